// Round 1
// 716.240 us; speedup vs baseline: 1.0047x; 1.0047x over previous
//
#include <hip/hip_runtime.h>
#include <math.h>

#define B_DIM   128
#define IN_DIM  1024
#define OUT_DIM 1024
#define IC      8                   // i-chunks (parallelism over the reduction dim)
#define ILEN    (IN_DIM / IC)       // 128

// Fast, numerically stable softplus: max(v,0) + log(1 + exp(-|v|)).
// __expf/__logf lower to v_exp_f32/v_log_f32 (trans pipe). Args to __logf are in
// [1,2] -> abs error ~1e-7; inputs are ~N(0,1) so no range issues. Well inside
// the harness absmax tolerance (0.5).
__device__ __forceinline__ float softplus_f(float v) {
    return fmaxf(v, 0.f) + __logf(1.f + __expf(-fabsf(v)));
}

// out[b,o] = eps_bias[b,o] * softplus(ro_bias[o]) + mu_bias[o]
__global__ __launch_bounds__(256) void bias_init_kernel(
    const float* __restrict__ eps_bias,
    const float* __restrict__ ro_bias,
    const float* __restrict__ mu_bias,
    float* __restrict__ out)
{
    int idx = blockIdx.x * 256 + threadIdx.x;       // 0 .. B*OUT-1
    int o = idx & (OUT_DIM - 1);
    out[idx] = fmaf(eps_bias[idx], softplus_f(ro_bias[o]), mu_bias[o]);
}

// Main: out[b,o] += sum_{i in chunk} x[b,i] * (eps[b,i,o]*softplus(ro[i,o]) + mu[i,o])
// Grid: B_DIM * IC blocks. ic = blockIdx & 7 so round-robin XCD dispatch gives
// each XCD one i-chunk -> its 1 MB ro+mu slice stays L2-resident.
//
// NOTE: deliberately NO workspace use this round. The previous version staged
// softplus(ro) into d_ws; rocprof showed the timed region dominated by two
// 2 GiB fillBufferAligned dispatches (~670 us) = workspace re-poison. Softplus
// is recomputed in-flight instead (~134M fast softplus, est. <20 us of
// overlappable VALU/trans work).
__global__ __launch_bounds__(256) void bayes_main_kernel(
    const float* __restrict__ x,
    const float* __restrict__ mu,
    const float* __restrict__ ro,
    const float* __restrict__ eps,
    float* __restrict__ out)
{
    const int ic = blockIdx.x & (IC - 1);
    const int b  = blockIdx.x >> 3;
    const int o  = threadIdx.x * 4;        // each thread owns 4 consecutive o
    const int i0 = ic * ILEN;

    const float* xp = x + b * IN_DIM + i0;
    const float* ep = eps + ((size_t)(b * IN_DIM + i0)) * OUT_DIM + o;
    const float* mp = mu + (size_t)i0 * OUT_DIM + o;
    const float* rp = ro + (size_t)i0 * OUT_DIM + o;

    float4 acc = make_float4(0.f, 0.f, 0.f, 0.f);

    #pragma unroll 4
    for (int i = 0; i < ILEN; ++i) {
        float xv = xp[i];                  // block-uniform -> scalar load
        float4 e = *(const float4*)ep;     // HBM stream, 16B/lane coalesced
        float4 m = *(const float4*)mp;     // L2-resident (1 MB slice per XCD)
        float4 s = *(const float4*)rp;     // L2-resident
        s.x = softplus_f(s.x);
        s.y = softplus_f(s.y);
        s.z = softplus_f(s.z);
        s.w = softplus_f(s.w);
        acc.x = fmaf(xv, fmaf(e.x, s.x, m.x), acc.x);
        acc.y = fmaf(xv, fmaf(e.y, s.y, m.y), acc.y);
        acc.z = fmaf(xv, fmaf(e.z, s.z, m.z), acc.z);
        acc.w = fmaf(xv, fmaf(e.w, s.w, m.w), acc.w);
        ep += OUT_DIM;
        mp += OUT_DIM;
        rp += OUT_DIM;
    }

    float* op = out + b * OUT_DIM + o;
    atomicAdd(op + 0, acc.x);
    atomicAdd(op + 1, acc.y);
    atomicAdd(op + 2, acc.z);
    atomicAdd(op + 3, acc.w);
}

extern "C" void kernel_launch(void* const* d_in, const int* in_sizes, int n_in,
                              void* d_out, int out_size, void* d_ws, size_t ws_size,
                              hipStream_t stream) {
    const float* x        = (const float*)d_in[0];
    const float* mu       = (const float*)d_in[1];
    const float* ro       = (const float*)d_in[2];
    const float* mu_bias  = (const float*)d_in[3];
    const float* ro_bias  = (const float*)d_in[4];
    const float* eps      = (const float*)d_in[5];
    const float* eps_bias = (const float*)d_in[6];
    float* out = (float*)d_out;

    (void)d_ws; (void)ws_size;   // workspace intentionally unused (poison-fill cost)

    // 1) out = bias term (overwrites poison)
    bias_init_kernel<<<(B_DIM * OUT_DIM) / 256, 256, 0, stream>>>(
        eps_bias, ro_bias, mu_bias, out);

    // 2) main accumulation, softplus in-flight
    bayes_main_kernel<<<B_DIM * IC, 256, 0, stream>>>(x, mu, ro, eps, out);
}